// Round 5
// baseline (162.478 us; speedup 1.0000x reference)
//
#include <hip/hip_runtime.h>
#include <hip/hip_bf16.h>
#include <cstddef>

// Shapes (fixed by the problem)
#define BB 8
#define TT 512
#define CC 512
#define NHH 8
#define HDD 64

typedef __attribute__((ext_vector_type(8))) short short8;
typedef __attribute__((ext_vector_type(4))) float f32x4;

__device__ __forceinline__ unsigned short f2bf(float f) {
    unsigned u = __float_as_uint(f);
    u += 0x7FFFu + ((u >> 16) & 1u);
    return (unsigned short)(u >> 16);
}
__device__ __forceinline__ float bf2f(unsigned short h) {
    return __uint_as_float(((unsigned)h) << 16);
}
__device__ __forceinline__ short8 cvt8(float4 a, float4 b) {
    unsigned short t[8] = {f2bf(a.x), f2bf(a.y), f2bf(a.z), f2bf(a.w),
                           f2bf(b.x), f2bf(b.y), f2bf(b.z), f2bf(b.w)};
    return *(const short8*)t;
}

// ---------------------------------------------------------------------------
// Kernel 1: QKV GEMM via MFMA, inline fp32->bf16 conversion in staging.
//   C[m][n] = x[m][:] . w[n][:] + bias[n].  Tile 128x128, BK=64, 4 waves.
//   q/k -> qkbuf bf16 [4096][1024]; v -> in-LDS transpose -> VT bf16 [b][h][d][t]
// ---------------------------------------------------------------------------
__global__ __launch_bounds__(256, 2) void gemm_qkv_mfma(
    const float* __restrict__ x, const float* __restrict__ w,
    const float* __restrict__ bias, unsigned short* __restrict__ qkbuf,
    unsigned short* __restrict__ VT)
{
    __shared__ __align__(16) unsigned short lds[128 * 136];

    const int tid = threadIdx.x;
    const int wv = tid >> 6, lane = tid & 63;
    const int c = lane & 15, quad = lane >> 4;
    const int wm = wv >> 1, wn = wv & 1;
    const int bm = blockIdx.y * 128, bn = blockIdx.x * 128;

    // staging source pointers (fp32): wave wv stages chunks wv*8 .. wv*8+7
    const float* pp[8];
#pragma unroll
    for (int l = 0; l < 8; ++l) {
        const int ci = wv * 8 + l;
        if (ci < 16) {
            const int m16 = ci >> 1, kk = ci & 1;
            pp[l] = x + (size_t)(bm + m16 * 16 + c) * 512 + kk * 32 + quad * 8;
        } else {
            const int cb = ci - 16, n16 = cb >> 1, kk = cb & 1;
            pp[l] = w + (size_t)(bn + n16 * 16 + c) * 512 + kk * 32 + quad * 8;
        }
    }

    f32x4 acc[4][4];
#pragma unroll
    for (int i = 0; i < 4; ++i)
#pragma unroll
        for (int j = 0; j < 4; ++j) acc[i][j] = (f32x4){0.f, 0.f, 0.f, 0.f};

    float4 pre0[8], pre1[8];
#pragma unroll
    for (int l = 0; l < 8; ++l) {
        pre0[l] = *(const float4*)pp[l];
        pre1[l] = *(const float4*)(pp[l] + 4);
    }

    for (int k0 = 0; k0 < 512; k0 += 64) {
        __syncthreads();
#pragma unroll
        for (int l = 0; l < 8; ++l)
            *(short8*)&lds[(wv * 8 + l) * 512 + lane * 8] = cvt8(pre0[l], pre1[l]);
        __syncthreads();
        if (k0 + 64 < 512) {
#pragma unroll
            for (int l = 0; l < 8; ++l) {
                pre0[l] = *(const float4*)(pp[l] + k0 + 64);
                pre1[l] = *(const float4*)(pp[l] + k0 + 68);
            }
        }
#pragma unroll
        for (int kk = 0; kk < 2; ++kk) {
            short8 af[4], bfr[4];
#pragma unroll
            for (int i = 0; i < 4; ++i)
                af[i] = *(const short8*)&lds[((wm * 4 + i) * 2 + kk) * 512 + lane * 8];
#pragma unroll
            for (int j = 0; j < 4; ++j)
                bfr[j] = *(const short8*)&lds[(16 + (wn * 4 + j) * 2 + kk) * 512 + lane * 8];
#pragma unroll
            for (int i = 0; i < 4; ++i)
#pragma unroll
                for (int j = 0; j < 4; ++j)
                    acc[i][j] = __builtin_amdgcn_mfma_f32_16x16x32_bf16(
                        af[i], bfr[j], acc[i][j], 0, 0, 0);
        }
    }

    float bj[4];
#pragma unroll
    for (int j = 0; j < 4; ++j) bj[j] = bias[bn + wn * 64 + j * 16 + c];

    if (bn < 1024) {
        // q/k: bf16 store, row-major [m][1024]
#pragma unroll
        for (int i = 0; i < 4; ++i)
#pragma unroll
            for (int j = 0; j < 4; ++j) {
                const int n = bn + wn * 64 + j * 16 + c;
#pragma unroll
                for (int r = 0; r < 4; ++r) {
                    const int m = bm + wm * 64 + i * 16 + quad * 4 + r;
                    qkbuf[(size_t)m * 1024 + n] = f2bf(acc[i][j][r] + bj[j]);
                }
            }
    } else {
        // v: bias + bf16, transpose in LDS -> VT[b][h][d][t]
        __syncthreads();
#pragma unroll
        for (int i = 0; i < 4; ++i)
#pragma unroll
            for (int j = 0; j < 4; ++j) {
                const int col = wn * 64 + j * 16 + c;
                const int row0 = wm * 64 + i * 16 + quad * 4;
                unsigned short t4[4];
#pragma unroll
                for (int r = 0; r < 4; ++r) t4[r] = f2bf(acc[i][j][r] + bj[j]);
                *(uint2*)&lds[col * 136 + row0] = *(const uint2*)t4;
            }
        __syncthreads();
        const int bi = bm >> 9, tb = bm & 511;
        const int hd0 = bn - 1024;
#pragma unroll
        for (int l = 0; l < 8; ++l) {
            const int idx = l * 256 + tid;
            const int col = idx >> 4, grp = idx & 15;
            const short8 v = *(const short8*)&lds[col * 136 + grp * 8];
            const int hd = hd0 + col, h = hd >> 6, d = hd & 63;
            *(short8*)(VT + ((size_t)(bi * NHH + h) * HDD + d) * TT + tb + grp * 8) = v;
        }
    }
}

// ---------------------------------------------------------------------------
// Kernel 2: LayerNorm over C=512 on q and k (bf16 in, bf16 head-major out).
//   One wave per (b,t) row; 8 elems/lane/stream; shuffle-only reduction.
// ---------------------------------------------------------------------------
__global__ __launch_bounds__(256) void ln_k(
    const unsigned short* __restrict__ qkbuf,
    const float* __restrict__ qg, const float* __restrict__ qb,
    const float* __restrict__ kg, const float* __restrict__ kb,
    unsigned short* __restrict__ Qh, unsigned short* __restrict__ Kh)
{
    const int wv = threadIdx.x >> 6, lane = threadIdx.x & 63;
    const int row = blockIdx.x * 4 + wv;
    const int bi = row >> 9, t = row & 511;
    const unsigned short* base = qkbuf + (size_t)row * 1024;

#pragma unroll
    for (int s = 0; s < 2; ++s) {
        const short8 v8 = *(const short8*)(base + s * 512 + lane * 8);
        float vf[8];
#pragma unroll
        for (int i = 0; i < 8; ++i) vf[i] = bf2f(((const unsigned short*)&v8)[i]);
        float sum = 0.f, sq = 0.f;
#pragma unroll
        for (int i = 0; i < 8; ++i) { sum += vf[i]; sq += vf[i] * vf[i]; }
#pragma unroll
        for (int off = 1; off < 64; off <<= 1) {
            sum += __shfl_xor(sum, off);
            sq += __shfl_xor(sq, off);
        }
        const float mu = sum * (1.f / 512.f);
        const float var = sq * (1.f / 512.f) - mu * mu;
        const float rsg = rsqrtf(var + 1e-5f);
        const float* gam = (s ? kg : qg) + lane * 8;
        const float* bet = (s ? kb : qb) + lane * 8;
        const float4 g0 = *(const float4*)gam, g1 = *(const float4*)(gam + 4);
        const float4 b0 = *(const float4*)bet, b1 = *(const float4*)(bet + 4);
        const float gv[8] = {g0.x, g0.y, g0.z, g0.w, g1.x, g1.y, g1.z, g1.w};
        const float bv[8] = {b0.x, b0.y, b0.z, b0.w, b1.x, b1.y, b1.z, b1.w};
        unsigned short o8[8];
#pragma unroll
        for (int i = 0; i < 8; ++i)
            o8[i] = f2bf((vf[i] - mu) * rsg * gv[i] + bv[i]);
        unsigned short* outp = s ? Kh : Qh;
        // col0 = lane*8 -> h = lane>>3, d = (lane&7)*8
        *(short8*)(outp + ((size_t)(bi * NHH + (lane >> 3)) * TT + t) * HDD
                   + (lane & 7) * 8) = *(const short8*)o8;
    }
}

// ---------------------------------------------------------------------------
// Kernel 3: MFMA flash attention with relative-position bias.
//   R5: flat 512-block grid, qt-complementary swizzle so co-resident block
//   pairs (i, i+256) have (qt, 7-qt) -> balanced 9 k-tile iters per CU.
//   Rel staged inline from fp32. Circular RD buffer (delta & 127) from R4.
// ---------------------------------------------------------------------------
#define RD_BODY(nr_)                                                            \
    {                                                                           \
        const short8 br0 = *(const short8*)&Rels[((nr_) * 2 + 0) * 512 + lane * 8]; \
        const short8 br1 = *(const short8*)&Rels[((nr_) * 2 + 1) * 512 + lane * 8]; \
        f32x4 a2 = (f32x4){0.f, 0.f, 0.f, 0.f};                                 \
        a2 = __builtin_amdgcn_mfma_f32_16x16x32_bf16(aq0, br0, a2, 0, 0, 0);    \
        a2 = __builtin_amdgcn_mfma_f32_16x16x32_bf16(aq1, br1, a2, 0, 0, 0);    \
        const int colw = (mbase + (nr_) * 16 + c) & 127;                        \
        _Pragma("unroll")                                                       \
        for (int r = 0; r < 4; ++r)                                             \
            RDs[w][(quad * 4 + r) * 132 + colw] = f2bf(a2[r]);                  \
    }

__global__ __launch_bounds__(256, 2) void attn_k(
    const unsigned short* __restrict__ Qh, const unsigned short* __restrict__ Kh,
    const unsigned short* __restrict__ VT, const float* __restrict__ rel,
    unsigned short* __restrict__ Yb)
{
    __shared__ __align__(16) unsigned short Qs[8 * 512];
    __shared__ __align__(16) unsigned short Ks[8 * 512];
    __shared__ __align__(16) unsigned short Vs[8 * 512];
    __shared__ __align__(16) unsigned short Rels[16 * 512];
    __shared__ __align__(16) unsigned short Ps[4][16 * 72];
    __shared__ __align__(16) unsigned short RDs[4][16 * 132];

    const int tid = threadIdx.x;
    const int w = tid >> 6;
    const int lane = tid & 63;
    const int c = lane & 15;
    const int quad = lane >> 4;

    // balanced swizzle: pairs (bid, bid+256) get complementary qt
    const int bid = blockIdx.x;
    const int half = bid >> 8, rr_ = bid & 255;
    const int qt0 = rr_ & 7;
    const int qt = half ? 7 - qt0 : qt0;
    const int h = (rr_ >> 3) & 7;
    const int b = (rr_ >> 6) + half * 4;
    const int i0 = qt * 64;

    const unsigned short* Qbase = Qh + (size_t)(b * NHH + h) * TT * HDD;
    const unsigned short* Kbase = Kh + (size_t)(b * NHH + h) * TT * HDD;
    const unsigned short* Vbase = VT + (size_t)(b * NHH + h) * HDD * TT;
    const float* Rbase = rel + h * HDD;   // fp32, row stride CC

#pragma unroll
    for (int kk = 0; kk < 2; ++kk) {
        const unsigned short* gp =
            Qbase + (size_t)(i0 + w * 16 + c) * HDD + kk * 32 + quad * 8;
        *(short8*)&Qs[(w * 2 + kk) * 512 + lane * 8] = *(const short8*)gp;
    }

    f32x4 oacc[4];
    float m_i[4], l_i[4];
#pragma unroll
    for (int r = 0; r < 4; ++r) { m_i[r] = -1e30f; l_i[r] = 0.f; }
#pragma unroll
    for (int nd = 0; nd < 4; ++nd) oacc[nd] = (f32x4){0.f, 0.f, 0.f, 0.f};

    short8 aq0, aq1;

    for (int jt = 0; jt <= qt; ++jt) {
        const int j0 = jt * 64;
#pragma unroll
        for (int kk = 0; kk < 2; ++kk) {
            const unsigned short* gp =
                Kbase + (size_t)(j0 + w * 16 + c) * HDD + kk * 32 + quad * 8;
            *(short8*)&Ks[(w * 2 + kk) * 512 + lane * 8] = *(const short8*)gp;
        }
#pragma unroll
        for (int js = 0; js < 2; ++js) {
            const unsigned short* gp =
                Vbase + (size_t)(w * 16 + c) * TT + j0 + js * 32 + quad * 8;
            *(short8*)&Vs[(w * 2 + js) * 512 + lane * 8] = *(const short8*)gp;
        }
        // rel window staging (inline fp32->bf16): first iter 128 deltas, later 64
        const int mbase = i0 - j0 - 63;
        if (jt == 0) {
#pragma unroll
            for (int sb = 0; sb < 2; ++sb) {
#pragma unroll
                for (int kk = 0; kk < 2; ++kk) {
                    const int n16 = w * 2 + sb;
                    int mrow = mbase + n16 * 16 + c;
                    mrow = mrow < 0 ? 0 : (mrow > 511 ? 511 : mrow);
                    const float* gp = Rbase + (size_t)mrow * CC + kk * 32 + quad * 8;
                    *(short8*)&Rels[(n16 * 2 + kk) * 512 + lane * 8] =
                        cvt8(*(const float4*)gp, *(const float4*)(gp + 4));
                }
            }
        } else {
#pragma unroll
            for (int kk = 0; kk < 2; ++kk) {
                int mrow = mbase + w * 16 + c;
                mrow = mrow < 0 ? 0 : (mrow > 511 ? 511 : mrow);
                const float* gp = Rbase + (size_t)mrow * CC + kk * 32 + quad * 8;
                *(short8*)&Rels[(w * 2 + kk) * 512 + lane * 8] =
                    cvt8(*(const float4*)gp, *(const float4*)(gp + 4));
            }
        }
        __syncthreads();

        if (jt == 0) {
            aq0 = *(const short8*)&Qs[(w * 2 + 0) * 512 + lane * 8];
            aq1 = *(const short8*)&Qs[(w * 2 + 1) * 512 + lane * 8];
        }

        // S = Q @ K^T
        f32x4 sAcc[4];
#pragma unroll
        for (int ns = 0; ns < 4; ++ns) {
            const short8 bk0 = *(const short8*)&Ks[(ns * 2 + 0) * 512 + lane * 8];
            const short8 bk1 = *(const short8*)&Ks[(ns * 2 + 1) * 512 + lane * 8];
            f32x4 a2 = (f32x4){0.f, 0.f, 0.f, 0.f};
            a2 = __builtin_amdgcn_mfma_f32_16x16x32_bf16(aq0, bk0, a2, 0, 0, 0);
            a2 = __builtin_amdgcn_mfma_f32_16x16x32_bf16(aq1, bk1, a2, 0, 0, 0);
            sAcc[ns] = a2;
        }
        // RD: only new delta subtiles
        if (jt == 0) {
#pragma unroll
            for (int nr = 0; nr < 8; ++nr) RD_BODY(nr)
        } else {
#pragma unroll
            for (int nr = 0; nr < 4; ++nr) RD_BODY(nr)
        }

        // gather rel bias (circular col = delta & 127), scale, causal mask
        const int dbase = i0 - j0;
        float sc[4][4];
#pragma unroll
        for (int ns = 0; ns < 4; ++ns) {
#pragma unroll
            for (int r = 0; r < 4; ++r) {
                const int r16 = quad * 4 + r;
                const int jc = ns * 16 + c;
                const int dp = (dbase + w * 16 + r16 - jc) & 127;
                const float rdv = bf2f(RDs[w][r16 * 132 + dp]);
                const float v = (sAcc[ns][r] + rdv) * 0.125f;
                sc[ns][r] = (j0 + jc > i0 + w * 16 + r16) ? -1e30f : v;
            }
        }
        float alpha[4];
#pragma unroll
        for (int r = 0; r < 4; ++r) {
            float m = fmaxf(fmaxf(sc[0][r], sc[1][r]), fmaxf(sc[2][r], sc[3][r]));
#pragma unroll
            for (int off = 1; off < 16; off <<= 1) m = fmaxf(m, __shfl_xor(m, off));
            const float mn = fmaxf(m_i[r], m);
            alpha[r] = __expf(m_i[r] - mn);
            m_i[r] = mn;
        }
        float rs[4] = {0.f, 0.f, 0.f, 0.f};
#pragma unroll
        for (int ns = 0; ns < 4; ++ns) {
#pragma unroll
            for (int r = 0; r < 4; ++r) {
                const float p = __expf(sc[ns][r] - m_i[r]);
                rs[r] += p;
                Ps[w][(quad * 4 + r) * 72 + ns * 16 + c] = f2bf(p);
            }
        }
#pragma unroll
        for (int r = 0; r < 4; ++r) {
#pragma unroll
            for (int off = 1; off < 16; off <<= 1) rs[r] += __shfl_xor(rs[r], off);
            l_i[r] = l_i[r] * alpha[r] + rs[r];
        }
#pragma unroll
        for (int nd = 0; nd < 4; ++nd)
#pragma unroll
            for (int r = 0; r < 4; ++r) oacc[nd][r] *= alpha[r];

        const short8 ap0 = *(const short8*)&Ps[w][c * 72 + 0 * 32 + quad * 8];
        const short8 ap1 = *(const short8*)&Ps[w][c * 72 + 1 * 32 + quad * 8];
#pragma unroll
        for (int nd = 0; nd < 4; ++nd) {
            const short8 bv0 = *(const short8*)&Vs[(nd * 2 + 0) * 512 + lane * 8];
            const short8 bv1 = *(const short8*)&Vs[(nd * 2 + 1) * 512 + lane * 8];
            oacc[nd] = __builtin_amdgcn_mfma_f32_16x16x32_bf16(ap0, bv0, oacc[nd], 0, 0, 0);
            oacc[nd] = __builtin_amdgcn_mfma_f32_16x16x32_bf16(ap1, bv1, oacc[nd], 0, 0, 0);
        }
        __syncthreads();
    }

    // epilogue: Yb[b][t][h*64 + d] bf16
#pragma unroll
    for (int r = 0; r < 4; ++r) {
        const float inv = 1.f / l_i[r];
        const int trow = i0 + w * 16 + quad * 4 + r;
        unsigned short* yb = Yb + ((size_t)b * TT + trow) * CC + h * HDD;
#pragma unroll
        for (int nd = 0; nd < 4; ++nd)
            yb[nd * 16 + c] = f2bf(oacc[nd][r] * inv);
    }
}

// ---------------------------------------------------------------------------
// Kernel 4: out = Yb @ w_proj^T + b_proj via MFMA, inline w_proj conversion.
//   Tile 64x128, BK=64, 4 waves (2x2 of 32x64). 256 blocks.
// ---------------------------------------------------------------------------
__global__ __launch_bounds__(256, 2) void gemm_proj_mfma(
    const unsigned short* __restrict__ Yb, const float* __restrict__ Wp,
    const float* __restrict__ bias, float* __restrict__ out)
{
    __shared__ __align__(16) unsigned short lds[24 * 512];  // A chunks 0..7, B 8..23

    const int tid = threadIdx.x;
    const int w = tid >> 6, lane = tid & 63;
    const int c = lane & 15, quad = lane >> 4;
    const int wm = w >> 1, wn = w & 1;
    const int bm = blockIdx.y * 64, bn = blockIdx.x * 128;

    const unsigned short* ppA[6];
    const float* ppB[6];
#pragma unroll
    for (int l = 0; l < 6; ++l) {
        const int ci = w * 6 + l;
        if (ci < 8) {
            const int m16 = ci >> 1, kk = ci & 1;
            ppA[l] = Yb + (size_t)(bm + m16 * 16 + c) * 512 + kk * 32 + quad * 8;
            ppB[l] = nullptr;
        } else {
            const int cb = ci - 8, n16 = cb >> 1, kk = cb & 1;
            ppA[l] = nullptr;
            ppB[l] = Wp + (size_t)(bn + n16 * 16 + c) * 512 + kk * 32 + quad * 8;
        }
    }

    f32x4 acc[2][4];
#pragma unroll
    for (int i = 0; i < 2; ++i)
#pragma unroll
        for (int j = 0; j < 4; ++j) acc[i][j] = (f32x4){0.f, 0.f, 0.f, 0.f};

    short8 preA[6];
    float4 preB0[6], preB1[6];
#pragma unroll
    for (int l = 0; l < 6; ++l) {
        if (ppA[l]) preA[l] = *(const short8*)ppA[l];
        else { preB0[l] = *(const float4*)ppB[l]; preB1[l] = *(const float4*)(ppB[l] + 4); }
    }

    for (int k0 = 0; k0 < 512; k0 += 64) {
        __syncthreads();
#pragma unroll
        for (int l = 0; l < 6; ++l) {
            const short8 v = ppA[l] ? preA[l] : cvt8(preB0[l], preB1[l]);
            *(short8*)&lds[(w * 6 + l) * 512 + lane * 8] = v;
        }
        __syncthreads();
        if (k0 + 64 < 512) {
#pragma unroll
            for (int l = 0; l < 6; ++l) {
                if (ppA[l]) preA[l] = *(const short8*)(ppA[l] + k0 + 64);
                else {
                    preB0[l] = *(const float4*)(ppB[l] + k0 + 64);
                    preB1[l] = *(const float4*)(ppB[l] + k0 + 68);
                }
            }
        }
#pragma unroll
        for (int kk = 0; kk < 2; ++kk) {
            short8 af[2], bfr[4];
#pragma unroll
            for (int i = 0; i < 2; ++i)
                af[i] = *(const short8*)&lds[((wm * 2 + i) * 2 + kk) * 512 + lane * 8];
#pragma unroll
            for (int j = 0; j < 4; ++j)
                bfr[j] = *(const short8*)&lds[(8 + (wn * 4 + j) * 2 + kk) * 512 + lane * 8];
#pragma unroll
            for (int i = 0; i < 2; ++i)
#pragma unroll
                for (int j = 0; j < 4; ++j)
                    acc[i][j] = __builtin_amdgcn_mfma_f32_16x16x32_bf16(
                        af[i], bfr[j], acc[i][j], 0, 0, 0);
        }
    }

#pragma unroll
    for (int j = 0; j < 4; ++j) {
        const int n = bn + wn * 64 + j * 16 + c;
        const float bj = bias[n];
#pragma unroll
        for (int i = 0; i < 2; ++i)
#pragma unroll
            for (int r = 0; r < 4; ++r) {
                const int m = bm + wm * 32 + i * 16 + quad * 4 + r;
                out[(size_t)m * 512 + n] = acc[i][j][r] + bj;
            }
    }
}

// ---------------------------------------------------------------------------
extern "C" void kernel_launch(void* const* d_in, const int* in_sizes, int n_in,
                              void* d_out, int out_size, void* d_ws, size_t ws_size,
                              hipStream_t stream)
{
    const float* x      = (const float*)d_in[0];
    const float* w_attn = (const float*)d_in[1];
    const float* b_attn = (const float*)d_in[2];
    const float* w_proj = (const float*)d_in[3];
    const float* b_proj = (const float*)d_in[4];
    const float* q_g    = (const float*)d_in[5];
    const float* q_b    = (const float*)d_in[6];
    const float* k_g    = (const float*)d_in[7];
    const float* k_b    = (const float*)d_in[8];
    const float* rel    = (const float*)d_in[9];
    float* out = (float*)d_out;

    // workspace (20 MB bf16): qkbuf [4096][1024] 8MB | Qh 4 | Kh 4 | VT 4
    // Yb (4MB) aliases qkbuf (dead after ln_k).
    unsigned short* qkbuf = (unsigned short*)d_ws;
    unsigned short* Qh = qkbuf + (size_t)4096 * 1024;
    unsigned short* Kh = Qh + (size_t)4096 * 512;
    unsigned short* VT = Kh + (size_t)4096 * 512;
    unsigned short* Yb = qkbuf;

    gemm_qkv_mfma<<<dim3(12, 32), 256, 0, stream>>>(x, w_attn, b_attn, qkbuf, VT);
    ln_k<<<1024, 256, 0, stream>>>(qkbuf, q_g, q_b, k_g, k_b, Qh, Kh);
    attn_k<<<512, 256, 0, stream>>>(Qh, Kh, VT, rel, Yb);
    gemm_proj_mfma<<<dim3(4, 64), 256, 0, stream>>>(Yb, w_proj, b_proj, out);
}

// Round 6
// 141.608 us; speedup vs baseline: 1.1474x; 1.1474x over previous
//
#include <hip/hip_runtime.h>
#include <hip/hip_bf16.h>
#include <cstddef>

// Shapes (fixed by the problem)
#define BB 8
#define TT 512
#define CC 512
#define NHH 8
#define HDD 64

typedef __attribute__((ext_vector_type(8))) short short8;
typedef __attribute__((ext_vector_type(4))) float f32x4;

__device__ __forceinline__ unsigned short f2bf(float f) {
    unsigned u = __float_as_uint(f);
    u += 0x7FFFu + ((u >> 16) & 1u);
    return (unsigned short)(u >> 16);
}
__device__ __forceinline__ float bf2f(unsigned short h) {
    return __uint_as_float(((unsigned)h) << 16);
}

// ---------------------------------------------------------------------------
// Kernel 0: fused fp32 -> bf16 convert for x / w_attn / w_proj / rel.
//   [0,2048) x, [2048,2816) w_attn, [2816,3072) w_proj, [3072,3328) rel.
// ---------------------------------------------------------------------------
__global__ __launch_bounds__(256) void cvt_all_k(
    const float* __restrict__ x, const float* __restrict__ wa,
    const float* __restrict__ wp, const float* __restrict__ rel,
    unsigned short* __restrict__ Xb, unsigned short* __restrict__ Wqb,
    unsigned short* __restrict__ Wpb, unsigned short* __restrict__ Relb)
{
    const int bidx = blockIdx.x;
    const float* in;
    unsigned short* out;
    int base;
    if (bidx < 2048)      { in = x;   out = Xb;   base = bidx; }
    else if (bidx < 2816) { in = wa;  out = Wqb;  base = bidx - 2048; }
    else if (bidx < 3072) { in = wp;  out = Wpb;  base = bidx - 2816; }
    else                  { in = rel; out = Relb; base = bidx - 3072; }
    const int i = base * 1024 + threadIdx.x * 4;
    const float4 v = *(const float4*)(in + i);
    unsigned short tmp[4] = {f2bf(v.x), f2bf(v.y), f2bf(v.z), f2bf(v.w)};
    *(uint2*)(out + i) = *(const uint2*)tmp;
}

// ---------------------------------------------------------------------------
// Kernel 1: QKV GEMM via MFMA (R4-proven bf16 staging).
//   q/k -> qkbuf bf16 [4096][1024]; v -> in-LDS transpose -> VT bf16 [b][h][d][t]
// ---------------------------------------------------------------------------
__global__ __launch_bounds__(256, 2) void gemm_qkv_mfma(
    const unsigned short* __restrict__ Xb, const unsigned short* __restrict__ Wb,
    const float* __restrict__ bias, unsigned short* __restrict__ qkbuf,
    unsigned short* __restrict__ VT)
{
    __shared__ __align__(16) unsigned short lds[128 * 136];

    const int tid = threadIdx.x;
    const int w = tid >> 6, lane = tid & 63;
    const int c = lane & 15, quad = lane >> 4;
    const int wm = w >> 1, wn = w & 1;
    const int bm = blockIdx.y * 128, bn = blockIdx.x * 128;

    const unsigned short* pp[8];
#pragma unroll
    for (int l = 0; l < 8; ++l) {
        const int ci = w * 8 + l;
        if (ci < 16) {
            const int m16 = ci >> 1, kk = ci & 1;
            pp[l] = Xb + (size_t)(bm + m16 * 16 + c) * 512 + kk * 32 + quad * 8;
        } else {
            const int cb = ci - 16, n16 = cb >> 1, kk = cb & 1;
            pp[l] = Wb + (size_t)(bn + n16 * 16 + c) * 512 + kk * 32 + quad * 8;
        }
    }

    f32x4 acc[4][4];
#pragma unroll
    for (int i = 0; i < 4; ++i)
#pragma unroll
        for (int j = 0; j < 4; ++j) acc[i][j] = (f32x4){0.f, 0.f, 0.f, 0.f};

    short8 pre[8];
#pragma unroll
    for (int l = 0; l < 8; ++l) pre[l] = *(const short8*)pp[l];

    for (int k0 = 0; k0 < 512; k0 += 64) {
        __syncthreads();
#pragma unroll
        for (int l = 0; l < 8; ++l)
            *(short8*)&lds[(w * 8 + l) * 512 + lane * 8] = pre[l];
        __syncthreads();
        if (k0 + 64 < 512) {
#pragma unroll
            for (int l = 0; l < 8; ++l)
                pre[l] = *(const short8*)(pp[l] + k0 + 64);
        }
#pragma unroll
        for (int kk = 0; kk < 2; ++kk) {
            short8 af[4], bfr[4];
#pragma unroll
            for (int i = 0; i < 4; ++i)
                af[i] = *(const short8*)&lds[((wm * 4 + i) * 2 + kk) * 512 + lane * 8];
#pragma unroll
            for (int j = 0; j < 4; ++j)
                bfr[j] = *(const short8*)&lds[(16 + (wn * 4 + j) * 2 + kk) * 512 + lane * 8];
#pragma unroll
            for (int i = 0; i < 4; ++i)
#pragma unroll
                for (int j = 0; j < 4; ++j)
                    acc[i][j] = __builtin_amdgcn_mfma_f32_16x16x32_bf16(
                        af[i], bfr[j], acc[i][j], 0, 0, 0);
        }
    }

    float bj[4];
#pragma unroll
    for (int j = 0; j < 4; ++j) bj[j] = bias[bn + wn * 64 + j * 16 + c];

    if (bn < 1024) {
        // q/k: bf16 store, row-major [m][1024]
#pragma unroll
        for (int i = 0; i < 4; ++i)
#pragma unroll
            for (int j = 0; j < 4; ++j) {
                const int n = bn + wn * 64 + j * 16 + c;
#pragma unroll
                for (int r = 0; r < 4; ++r) {
                    const int m = bm + wm * 64 + i * 16 + quad * 4 + r;
                    qkbuf[(size_t)m * 1024 + n] = f2bf(acc[i][j][r] + bj[j]);
                }
            }
    } else {
        // v: bias + bf16, transpose in LDS -> VT[b][h][d][t]
        __syncthreads();
#pragma unroll
        for (int i = 0; i < 4; ++i)
#pragma unroll
            for (int j = 0; j < 4; ++j) {
                const int col = wn * 64 + j * 16 + c;
                const int row0 = wm * 64 + i * 16 + quad * 4;
                unsigned short t4[4];
#pragma unroll
                for (int r = 0; r < 4; ++r) t4[r] = f2bf(acc[i][j][r] + bj[j]);
                *(uint2*)&lds[col * 136 + row0] = *(const uint2*)t4;
            }
        __syncthreads();
        const int bi = bm >> 9, tb = bm & 511;
        const int hd0 = bn - 1024;
#pragma unroll
        for (int l = 0; l < 8; ++l) {
            const int idx = l * 256 + tid;
            const int col = idx >> 4, grp = idx & 15;
            const short8 v = *(const short8*)&lds[col * 136 + grp * 8];
            const int hd = hd0 + col, h = hd >> 6, d = hd & 63;
            *(short8*)(VT + ((size_t)(bi * NHH + h) * HDD + d) * TT + tb + grp * 8) = v;
        }
    }
}

// ---------------------------------------------------------------------------
// Kernel 2: LayerNorm over C=512 on q and k (bf16 in, bf16 head-major out).
//   One wave per (b,t) row; 8 elems/lane/stream; shuffle-only reduction.
// ---------------------------------------------------------------------------
__global__ __launch_bounds__(256) void ln_k(
    const unsigned short* __restrict__ qkbuf,
    const float* __restrict__ qg, const float* __restrict__ qb,
    const float* __restrict__ kg, const float* __restrict__ kb,
    unsigned short* __restrict__ Qh, unsigned short* __restrict__ Kh)
{
    const int wv = threadIdx.x >> 6, lane = threadIdx.x & 63;
    const int row = blockIdx.x * 4 + wv;
    const int bi = row >> 9, t = row & 511;
    const unsigned short* base = qkbuf + (size_t)row * 1024;

#pragma unroll
    for (int s = 0; s < 2; ++s) {
        const short8 v8 = *(const short8*)(base + s * 512 + lane * 8);
        float vf[8];
#pragma unroll
        for (int i = 0; i < 8; ++i) vf[i] = bf2f(((const unsigned short*)&v8)[i]);
        float sum = 0.f, sq = 0.f;
#pragma unroll
        for (int i = 0; i < 8; ++i) { sum += vf[i]; sq += vf[i] * vf[i]; }
#pragma unroll
        for (int off = 1; off < 64; off <<= 1) {
            sum += __shfl_xor(sum, off);
            sq += __shfl_xor(sq, off);
        }
        const float mu = sum * (1.f / 512.f);
        const float var = sq * (1.f / 512.f) - mu * mu;
        const float rsg = rsqrtf(var + 1e-5f);
        const float* gam = (s ? kg : qg) + lane * 8;
        const float* bet = (s ? kb : qb) + lane * 8;
        const float4 g0 = *(const float4*)gam, g1 = *(const float4*)(gam + 4);
        const float4 b0 = *(const float4*)bet, b1 = *(const float4*)(bet + 4);
        const float gv[8] = {g0.x, g0.y, g0.z, g0.w, g1.x, g1.y, g1.z, g1.w};
        const float bv[8] = {b0.x, b0.y, b0.z, b0.w, b1.x, b1.y, b1.z, b1.w};
        unsigned short o8[8];
#pragma unroll
        for (int i = 0; i < 8; ++i)
            o8[i] = f2bf((vf[i] - mu) * rsg * gv[i] + bv[i]);
        unsigned short* outp = s ? Kh : Qh;
        *(short8*)(outp + ((size_t)(bi * NHH + (lane >> 3)) * TT + t) * HDD
                   + (lane & 7) * 8) = *(const short8*)o8;
    }
}

// ---------------------------------------------------------------------------
// Kernel 3: MFMA flash attention with relative-position bias.
//   R6: pairing-robust qt swizzle. bid bits: 0->flip/b2, 1-3->q0, 4-6->h,
//   7->b0, 8->flip/b1.  s = bit0^bit8; qt = s ? 7-q0 : q0.
//   Both (2i,2i+1) and (i,i+256) co-resident pairings give complementary qt
//   -> every CU does (qt+1)+(8-qt)=9 k-tile iterations.
//   Circular RD buffer (delta & 127) from R4; Relb bf16.
// ---------------------------------------------------------------------------
#define RD_BODY(nr_)                                                            \
    {                                                                           \
        const short8 br0 = *(const short8*)&Rels[((nr_) * 2 + 0) * 512 + lane * 8]; \
        const short8 br1 = *(const short8*)&Rels[((nr_) * 2 + 1) * 512 + lane * 8]; \
        f32x4 a2 = (f32x4){0.f, 0.f, 0.f, 0.f};                                 \
        a2 = __builtin_amdgcn_mfma_f32_16x16x32_bf16(aq0, br0, a2, 0, 0, 0);    \
        a2 = __builtin_amdgcn_mfma_f32_16x16x32_bf16(aq1, br1, a2, 0, 0, 0);    \
        const int colw = (mbase + (nr_) * 16 + c) & 127;                        \
        _Pragma("unroll")                                                       \
        for (int r = 0; r < 4; ++r)                                             \
            RDs[w][(quad * 4 + r) * 132 + colw] = f2bf(a2[r]);                  \
    }

__global__ __launch_bounds__(256, 2) void attn_k(
    const unsigned short* __restrict__ Qh, const unsigned short* __restrict__ Kh,
    const unsigned short* __restrict__ VT, const unsigned short* __restrict__ Relb,
    unsigned short* __restrict__ Yb)
{
    __shared__ __align__(16) unsigned short Qs[8 * 512];
    __shared__ __align__(16) unsigned short Ks[8 * 512];
    __shared__ __align__(16) unsigned short Vs[8 * 512];
    __shared__ __align__(16) unsigned short Rels[16 * 512];
    __shared__ __align__(16) unsigned short Ps[4][16 * 72];
    __shared__ __align__(16) unsigned short RDs[4][16 * 132];

    const int tid = threadIdx.x;
    const int w = tid >> 6;
    const int lane = tid & 63;
    const int c = lane & 15;
    const int quad = lane >> 4;

    // pairing-robust balanced decode
    const int bid = blockIdx.x;
    const int bit0 = bid & 1, bit8 = (bid >> 8) & 1;
    const int s_ = bit0 ^ bit8;
    const int q0 = (bid >> 1) & 7;
    const int qt = s_ ? 7 - q0 : q0;
    const int h = (bid >> 4) & 7;
    const int b = ((bid >> 7) & 1) | (bit8 << 1) | (bit0 << 2);
    const int i0 = qt * 64;

    const unsigned short* Qbase = Qh + (size_t)(b * NHH + h) * TT * HDD;
    const unsigned short* Kbase = Kh + (size_t)(b * NHH + h) * TT * HDD;
    const unsigned short* Vbase = VT + (size_t)(b * NHH + h) * HDD * TT;
    const unsigned short* Rbase = Relb + h * HDD;

#pragma unroll
    for (int kk = 0; kk < 2; ++kk) {
        const unsigned short* gp =
            Qbase + (size_t)(i0 + w * 16 + c) * HDD + kk * 32 + quad * 8;
        *(short8*)&Qs[(w * 2 + kk) * 512 + lane * 8] = *(const short8*)gp;
    }

    f32x4 oacc[4];
    float m_i[4], l_i[4];
#pragma unroll
    for (int r = 0; r < 4; ++r) { m_i[r] = -1e30f; l_i[r] = 0.f; }
#pragma unroll
    for (int nd = 0; nd < 4; ++nd) oacc[nd] = (f32x4){0.f, 0.f, 0.f, 0.f};

    short8 aq0, aq1;

    for (int jt = 0; jt <= qt; ++jt) {
        const int j0 = jt * 64;
#pragma unroll
        for (int kk = 0; kk < 2; ++kk) {
            const unsigned short* gp =
                Kbase + (size_t)(j0 + w * 16 + c) * HDD + kk * 32 + quad * 8;
            *(short8*)&Ks[(w * 2 + kk) * 512 + lane * 8] = *(const short8*)gp;
        }
#pragma unroll
        for (int js = 0; js < 2; ++js) {
            const unsigned short* gp =
                Vbase + (size_t)(w * 16 + c) * TT + j0 + js * 32 + quad * 8;
            *(short8*)&Vs[(w * 2 + js) * 512 + lane * 8] = *(const short8*)gp;
        }
        // rel window staging: first iter 128 deltas, later 64 new
        const int mbase = i0 - j0 - 63;
        if (jt == 0) {
#pragma unroll
            for (int sb = 0; sb < 2; ++sb) {
#pragma unroll
                for (int kk = 0; kk < 2; ++kk) {
                    const int n16 = w * 2 + sb;
                    int mrow = mbase + n16 * 16 + c;
                    mrow = mrow < 0 ? 0 : (mrow > 511 ? 511 : mrow);
                    *(short8*)&Rels[(n16 * 2 + kk) * 512 + lane * 8] =
                        *(const short8*)(Rbase + (size_t)mrow * CC + kk * 32 + quad * 8);
                }
            }
        } else {
#pragma unroll
            for (int kk = 0; kk < 2; ++kk) {
                int mrow = mbase + w * 16 + c;
                mrow = mrow < 0 ? 0 : (mrow > 511 ? 511 : mrow);
                *(short8*)&Rels[(w * 2 + kk) * 512 + lane * 8] =
                    *(const short8*)(Rbase + (size_t)mrow * CC + kk * 32 + quad * 8);
            }
        }
        __syncthreads();

        if (jt == 0) {
            aq0 = *(const short8*)&Qs[(w * 2 + 0) * 512 + lane * 8];
            aq1 = *(const short8*)&Qs[(w * 2 + 1) * 512 + lane * 8];
        }

        // S = Q @ K^T
        f32x4 sAcc[4];
#pragma unroll
        for (int ns = 0; ns < 4; ++ns) {
            const short8 bk0 = *(const short8*)&Ks[(ns * 2 + 0) * 512 + lane * 8];
            const short8 bk1 = *(const short8*)&Ks[(ns * 2 + 1) * 512 + lane * 8];
            f32x4 a2 = (f32x4){0.f, 0.f, 0.f, 0.f};
            a2 = __builtin_amdgcn_mfma_f32_16x16x32_bf16(aq0, bk0, a2, 0, 0, 0);
            a2 = __builtin_amdgcn_mfma_f32_16x16x32_bf16(aq1, bk1, a2, 0, 0, 0);
            sAcc[ns] = a2;
        }
        // RD: only new delta subtiles
        if (jt == 0) {
#pragma unroll
            for (int nr = 0; nr < 8; ++nr) RD_BODY(nr)
        } else {
#pragma unroll
            for (int nr = 0; nr < 4; ++nr) RD_BODY(nr)
        }

        // gather rel bias (circular col = delta & 127), scale, causal mask
        const int dbase = i0 - j0;
        float sc[4][4];
#pragma unroll
        for (int ns = 0; ns < 4; ++ns) {
#pragma unroll
            for (int r = 0; r < 4; ++r) {
                const int r16 = quad * 4 + r;
                const int jc = ns * 16 + c;
                const int dp = (dbase + w * 16 + r16 - jc) & 127;
                const float rdv = bf2f(RDs[w][r16 * 132 + dp]);
                const float v = (sAcc[ns][r] + rdv) * 0.125f;
                sc[ns][r] = (j0 + jc > i0 + w * 16 + r16) ? -1e30f : v;
            }
        }
        float alpha[4];
#pragma unroll
        for (int r = 0; r < 4; ++r) {
            float m = fmaxf(fmaxf(sc[0][r], sc[1][r]), fmaxf(sc[2][r], sc[3][r]));
#pragma unroll
            for (int off = 1; off < 16; off <<= 1) m = fmaxf(m, __shfl_xor(m, off));
            const float mn = fmaxf(m_i[r], m);
            alpha[r] = __expf(m_i[r] - mn);
            m_i[r] = mn;
        }
        float rs[4] = {0.f, 0.f, 0.f, 0.f};
#pragma unroll
        for (int ns = 0; ns < 4; ++ns) {
#pragma unroll
            for (int r = 0; r < 4; ++r) {
                const float p = __expf(sc[ns][r] - m_i[r]);
                rs[r] += p;
                Ps[w][(quad * 4 + r) * 72 + ns * 16 + c] = f2bf(p);
            }
        }
#pragma unroll
        for (int r = 0; r < 4; ++r) {
#pragma unroll
            for (int off = 1; off < 16; off <<= 1) rs[r] += __shfl_xor(rs[r], off);
            l_i[r] = l_i[r] * alpha[r] + rs[r];
        }
#pragma unroll
        for (int nd = 0; nd < 4; ++nd)
#pragma unroll
            for (int r = 0; r < 4; ++r) oacc[nd][r] *= alpha[r];

        const short8 ap0 = *(const short8*)&Ps[w][c * 72 + 0 * 32 + quad * 8];
        const short8 ap1 = *(const short8*)&Ps[w][c * 72 + 1 * 32 + quad * 8];
#pragma unroll
        for (int nd = 0; nd < 4; ++nd) {
            const short8 bv0 = *(const short8*)&Vs[(nd * 2 + 0) * 512 + lane * 8];
            const short8 bv1 = *(const short8*)&Vs[(nd * 2 + 1) * 512 + lane * 8];
            oacc[nd] = __builtin_amdgcn_mfma_f32_16x16x32_bf16(ap0, bv0, oacc[nd], 0, 0, 0);
            oacc[nd] = __builtin_amdgcn_mfma_f32_16x16x32_bf16(ap1, bv1, oacc[nd], 0, 0, 0);
        }
        __syncthreads();
    }

    // epilogue: Yb[b][t][h*64 + d] bf16
#pragma unroll
    for (int r = 0; r < 4; ++r) {
        const float inv = 1.f / l_i[r];
        const int trow = i0 + w * 16 + quad * 4 + r;
        unsigned short* yb = Yb + ((size_t)b * TT + trow) * CC + h * HDD;
#pragma unroll
        for (int nd = 0; nd < 4; ++nd)
            yb[nd * 16 + c] = f2bf(oacc[nd][r] * inv);
    }
}

// ---------------------------------------------------------------------------
// Kernel 4: out = Yb @ Wpb^T + b_proj via MFMA (R4-proven bf16 staging).
//   Tile 64x128, BK=64, 4 waves (2x2 of 32x64). 256 blocks.
// ---------------------------------------------------------------------------
__global__ __launch_bounds__(256, 2) void gemm_proj_mfma(
    const unsigned short* __restrict__ Yb, const unsigned short* __restrict__ Wp,
    const float* __restrict__ bias, float* __restrict__ out)
{
    __shared__ __align__(16) unsigned short lds[24 * 512];

    const int tid = threadIdx.x;
    const int w = tid >> 6, lane = tid & 63;
    const int c = lane & 15, quad = lane >> 4;
    const int wm = w >> 1, wn = w & 1;
    const int bm = blockIdx.y * 64, bn = blockIdx.x * 128;

    const unsigned short* pp[6];
#pragma unroll
    for (int l = 0; l < 6; ++l) {
        const int ci = w * 6 + l;
        if (ci < 8) {
            const int m16 = ci >> 1, kk = ci & 1;
            pp[l] = Yb + (size_t)(bm + m16 * 16 + c) * 512 + kk * 32 + quad * 8;
        } else {
            const int cb = ci - 8, n16 = cb >> 1, kk = cb & 1;
            pp[l] = Wp + (size_t)(bn + n16 * 16 + c) * 512 + kk * 32 + quad * 8;
        }
    }

    f32x4 acc[2][4];
#pragma unroll
    for (int i = 0; i < 2; ++i)
#pragma unroll
        for (int j = 0; j < 4; ++j) acc[i][j] = (f32x4){0.f, 0.f, 0.f, 0.f};

    short8 pre[6];
#pragma unroll
    for (int l = 0; l < 6; ++l) pre[l] = *(const short8*)pp[l];

    for (int k0 = 0; k0 < 512; k0 += 64) {
        __syncthreads();
#pragma unroll
        for (int l = 0; l < 6; ++l)
            *(short8*)&lds[(w * 6 + l) * 512 + lane * 8] = pre[l];
        __syncthreads();
        if (k0 + 64 < 512) {
#pragma unroll
            for (int l = 0; l < 6; ++l)
                pre[l] = *(const short8*)(pp[l] + k0 + 64);
        }
#pragma unroll
        for (int kk = 0; kk < 2; ++kk) {
            short8 af[2], bfr[4];
#pragma unroll
            for (int i = 0; i < 2; ++i)
                af[i] = *(const short8*)&lds[((wm * 2 + i) * 2 + kk) * 512 + lane * 8];
#pragma unroll
            for (int j = 0; j < 4; ++j)
                bfr[j] = *(const short8*)&lds[(8 + (wn * 4 + j) * 2 + kk) * 512 + lane * 8];
#pragma unroll
            for (int i = 0; i < 2; ++i)
#pragma unroll
                for (int j = 0; j < 4; ++j)
                    acc[i][j] = __builtin_amdgcn_mfma_f32_16x16x32_bf16(
                        af[i], bfr[j], acc[i][j], 0, 0, 0);
        }
    }

#pragma unroll
    for (int j = 0; j < 4; ++j) {
        const int n = bn + wn * 64 + j * 16 + c;
        const float bj = bias[n];
#pragma unroll
        for (int i = 0; i < 2; ++i)
#pragma unroll
            for (int r = 0; r < 4; ++r) {
                const int m = bm + wm * 32 + i * 16 + quad * 4 + r;
                out[(size_t)m * 512 + n] = acc[i][j][r] + bj;
            }
    }
}

// ---------------------------------------------------------------------------
extern "C" void kernel_launch(void* const* d_in, const int* in_sizes, int n_in,
                              void* d_out, int out_size, void* d_ws, size_t ws_size,
                              hipStream_t stream)
{
    const float* x      = (const float*)d_in[0];
    const float* w_attn = (const float*)d_in[1];
    const float* b_attn = (const float*)d_in[2];
    const float* w_proj = (const float*)d_in[3];
    const float* b_proj = (const float*)d_in[4];
    const float* q_g    = (const float*)d_in[5];
    const float* q_b    = (const float*)d_in[6];
    const float* k_g    = (const float*)d_in[7];
    const float* k_b    = (const float*)d_in[8];
    const float* rel    = (const float*)d_in[9];
    float* out = (float*)d_out;

    // workspace (~26.5 MB bf16): qkbuf [4096][1024] 8MB | Qh 4 | Kh 4 | VT 4 |
    //   Relb 0.5 | Xb 4 | Wqb 1.5 | Wpb 0.5.  Yb (4MB) aliases qkbuf.
    unsigned short* qkbuf = (unsigned short*)d_ws;
    unsigned short* Qh   = qkbuf + (size_t)4096 * 1024;
    unsigned short* Kh   = Qh + (size_t)4096 * 512;
    unsigned short* VT   = Kh + (size_t)4096 * 512;
    unsigned short* Relb = VT + (size_t)4096 * 512;
    unsigned short* Xb   = Relb + (size_t)512 * 512;
    unsigned short* Wqb  = Xb + (size_t)4096 * 512;
    unsigned short* Wpb  = Wqb + (size_t)1536 * 512;
    unsigned short* Yb   = qkbuf;

    cvt_all_k<<<3328, 256, 0, stream>>>(x, w_attn, w_proj, rel, Xb, Wqb, Wpb, Relb);
    gemm_qkv_mfma<<<dim3(12, 32), 256, 0, stream>>>(Xb, Wqb, b_attn, qkbuf, VT);
    ln_k<<<1024, 256, 0, stream>>>(qkbuf, q_g, q_b, k_g, k_b, Qh, Kh);
    attn_k<<<512, 256, 0, stream>>>(Qh, Kh, VT, Relb, Yb);
    gemm_proj_mfma<<<dim3(4, 64), 256, 0, stream>>>(Yb, Wpb, b_proj, out);
}